// Round 1
// baseline (1261.991 us; speedup 1.0000x reference)
//
#include <hip/hip_runtime.h>

// ---------------- degree count ----------------
__global__ void k_count(const int* __restrict__ src, const int* __restrict__ dst,
                        int* __restrict__ deg_u, int* __restrict__ deg_m, int E) {
    int e = blockIdx.x * 256 + threadIdx.x;
    if (e >= E) return;
    atomicAdd(&deg_u[src[e]], 1);
    atomicAdd(&deg_m[dst[e]], 1);
}

// ---------------- 2-level inclusive scan -> exclusive offsets ----------------
__global__ void k_scan_local(const int* __restrict__ deg, int* __restrict__ scanned,
                             int* __restrict__ bsums, int N) {
    __shared__ int s[1024];
    int base = blockIdx.x * 1024;
    for (int t = threadIdx.x; t < 1024; t += 256) {
        int i = base + t;
        s[t] = (i < N) ? deg[i] : 0;
    }
    __syncthreads();
    for (int d = 1; d < 1024; d <<= 1) {
        int vals[4];
        for (int j = 0; j < 4; ++j) {
            int t = threadIdx.x + j * 256;
            vals[j] = (t >= d) ? s[t - d] : 0;
        }
        __syncthreads();
        for (int j = 0; j < 4; ++j) {
            int t = threadIdx.x + j * 256;
            s[t] += vals[j];
        }
        __syncthreads();
    }
    for (int t = threadIdx.x; t < 1024; t += 256) {
        int i = base + t;
        if (i < N) scanned[i] = s[t];
    }
    if (threadIdx.x == 0) bsums[blockIdx.x] = s[1023];
}

__global__ void k_scan_carry(int* bsums, int nb) {
    __shared__ int s[256];
    int t = threadIdx.x;
    s[t] = (t < nb) ? bsums[t] : 0;
    __syncthreads();
    for (int d = 1; d < 256; d <<= 1) {
        int v = (t >= d) ? s[t - d] : 0;
        __syncthreads();
        s[t] += v;
        __syncthreads();
    }
    if (t < nb) bsums[t] = s[t];
}

__global__ void k_scan_off(const int* __restrict__ scanned, const int* __restrict__ bsums,
                           int* __restrict__ off, int N) {
    int i = blockIdx.x * 256 + threadIdx.x;
    if (i > N) return;
    int v = 0;
    if (i > 0) {
        int j = i - 1;
        int b = j >> 10;
        v = scanned[j] + (b > 0 ? bsums[b - 1] : 0);
    }
    off[i] = v;
}

// ---------------- CSR fill ----------------
__global__ void k_fill(const int* __restrict__ src, const int* __restrict__ dst,
                       int* __restrict__ pos_u, int* __restrict__ pos_m,
                       int* __restrict__ adj_u, int* __restrict__ adj_m, int E) {
    int e = blockIdx.x * 256 + threadIdx.x;
    if (e >= E) return;
    int s = src[e], d = dst[e];
    int pm = atomicAdd(&pos_m[d], 1);
    adj_m[pm] = s;                 // per-movie list of user sources
    int pu = atomicAdd(&pos_u[s], 1);
    adj_u[pu] = d;                 // per-user list of movie dsts
}

// ---------------- movie projection: relu(movie_x @ proj_w + b) ----------------
__global__ __launch_bounds__(256) void k_proj(const float* __restrict__ mx,
                                              const float* __restrict__ w,
                                              const float* __restrict__ b,
                                              float* __restrict__ out, int M) {
    __shared__ float ws[256 * 64];   // 64 KB
    __shared__ float xs[4][256];
    for (int t = threadIdx.x; t < 256 * 64 / 4; t += 256)
        ((float4*)ws)[t] = ((const float4*)w)[t];
    int nl = threadIdx.x >> 6, j = threadIdx.x & 63;
    for (int n0 = blockIdx.x * 4; n0 < M; n0 += gridDim.x * 4) {
        __syncthreads();
        for (int t = threadIdx.x; t < 256; t += 256) {
            int r = t >> 6, c4 = t & 63;
            int n = n0 + r;
            float4 v = (n < M) ? ((const float4*)mx)[n * 64 + c4] : make_float4(0.f, 0.f, 0.f, 0.f);
            ((float4*)&xs[r][0])[c4] = v;
        }
        __syncthreads();
        int n = n0 + nl;
        if (n < M) {
            float acc = b[j];
            #pragma unroll 8
            for (int k = 0; k < 256; ++k)
                acc += xs[nl][k] * ws[k * 64 + j];
            out[n * 64 + j] = fmaxf(acc, 0.f);
        }
    }
}

// ---------------- gather-side segment mean: one wave per node ----------------
__global__ __launch_bounds__(256) void k_agg(const float* __restrict__ x,
                                             const int* __restrict__ adj,
                                             const int* __restrict__ off,
                                             float* __restrict__ out, int N) {
    int node = blockIdx.x * 4 + (threadIdx.x >> 6);
    int lane = threadIdx.x & 63;
    if (node >= N) return;
    node = __builtin_amdgcn_readfirstlane(node);
    int s0 = off[node], s1 = off[node + 1];
    float a0 = 0.f, a1 = 0.f;
    int e = s0;
    for (; e + 1 < s1; e += 2) {
        a0 += x[adj[e] * 64 + lane];
        a1 += x[adj[e + 1] * 64 + lane];
    }
    if (e < s1) a0 += x[adj[e] * 64 + lane];
    int deg = s1 - s0;
    float scale = (deg > 0) ? 1.0f / (float)deg : 0.f;
    out[node * 64 + lane] = (a0 + a1) * scale;
}

// ---------------- layer-1 transform + relu + residual ----------------
// res = self + relu(mean @ wl + bl + self @ wr)
__global__ __launch_bounds__(256) void k_trans1(const float* __restrict__ mean,
                                                const float* __restrict__ self,
                                                const float* __restrict__ wl,
                                                const float* __restrict__ bl,
                                                const float* __restrict__ wr,
                                                float* __restrict__ res, int N) {
    __shared__ float wls[4096], wrs[4096];
    __shared__ float ms[4][64], ss[4][64];
    for (int t = threadIdx.x; t < 1024; t += 256) {
        ((float4*)wls)[t] = ((const float4*)wl)[t];
        ((float4*)wrs)[t] = ((const float4*)wr)[t];
    }
    int nl = threadIdx.x >> 6, lane = threadIdx.x & 63;
    float bias = bl[lane];
    for (int n0 = blockIdx.x * 4; n0 < N; n0 += gridDim.x * 4) {
        int n = n0 + nl;
        __syncthreads();
        if (n < N) {
            ms[nl][lane] = mean[n * 64 + lane];
            ss[nl][lane] = self[n * 64 + lane];
        }
        __syncthreads();
        if (n < N) {
            float acc = bias;
            #pragma unroll 16
            for (int k = 0; k < 64; ++k)
                acc += ms[nl][k] * wls[k * 64 + lane] + ss[nl][k] * wrs[k * 64 + lane];
            res[n * 64 + lane] = ss[nl][lane] + fmaxf(acc, 0.f);
        }
    }
}

// ---------------- layer-2 transform + l2norm + decoder half-projection ----------------
// t = mean @ wl + bl + res @ wr ; t /= max(||t||, 1e-12) ; outA = t @ wd
// NOTE: outA may alias mean (in-place, row-exclusive) -> no __restrict__ on those.
__global__ __launch_bounds__(256) void k_trans2(const float* mean,
                                                const float* __restrict__ res,
                                                const float* __restrict__ wl,
                                                const float* __restrict__ bl,
                                                const float* __restrict__ wr,
                                                const float* __restrict__ wd,
                                                float* outA, int N) {
    __shared__ float wls[4096], wrs[4096], wds[4096];
    __shared__ float ms[4][64], ss[4][64], ts[4][64];
    for (int t = threadIdx.x; t < 1024; t += 256) {
        ((float4*)wls)[t] = ((const float4*)wl)[t];
        ((float4*)wrs)[t] = ((const float4*)wr)[t];
        ((float4*)wds)[t] = ((const float4*)wd)[t];
    }
    int nl = threadIdx.x >> 6, lane = threadIdx.x & 63;
    float bias = bl[lane];
    for (int n0 = blockIdx.x * 4; n0 < N; n0 += gridDim.x * 4) {
        int n = n0 + nl;
        __syncthreads();
        if (n < N) {
            ms[nl][lane] = mean[n * 64 + lane];
            ss[nl][lane] = res[n * 64 + lane];
        }
        __syncthreads();
        if (n < N) {
            float acc = bias;
            #pragma unroll 16
            for (int k = 0; k < 64; ++k)
                acc += ms[nl][k] * wls[k * 64 + lane] + ss[nl][k] * wrs[k * 64 + lane];
            float sq = acc * acc;
            #pragma unroll
            for (int o = 32; o > 0; o >>= 1) sq += __shfl_xor(sq, o, 64);
            ts[nl][lane] = acc / fmaxf(sqrtf(sq), 1e-12f);
        }
        __syncthreads();
        if (n < N) {
            float a = 0.f;
            #pragma unroll 16
            for (int k = 0; k < 64; ++k)
                a += ts[nl][k] * wds[k * 64 + lane];
            outA[n * 64 + lane] = a;
        }
    }
}

// ---------------- decoder: out = relu(A[ls]+B[ld]+b1) . w2 + b2 ----------------
__global__ __launch_bounds__(256) void k_dec(const float* __restrict__ A,
                                             const float* __restrict__ B,
                                             const int* __restrict__ ls,
                                             const int* __restrict__ ld,
                                             const float* __restrict__ b1,
                                             const float* __restrict__ w2,
                                             const float* __restrict__ b2,
                                             float* __restrict__ out, int EL) {
    int e = blockIdx.x * 4 + (threadIdx.x >> 6);
    int lane = threadIdx.x & 63;
    if (e >= EL) return;
    int u = ls[e], m = ld[e];
    float h = fmaxf(A[u * 64 + lane] + B[m * 64 + lane] + b1[lane], 0.f);
    float p = h * w2[lane];
    #pragma unroll
    for (int o = 32; o > 0; o >>= 1) p += __shfl_xor(p, o, 64);
    if (lane == 0) out[e] = p + b2[0];
}

extern "C" void kernel_launch(void* const* d_in, const int* in_sizes, int n_in,
                              void* d_out, int out_size, void* d_ws, size_t ws_size,
                              hipStream_t stream) {
    const float* movie_x  = (const float*)d_in[0];
    const float* user_emb = (const float*)d_in[1];
    const float* proj_w   = (const float*)d_in[2];
    const float* proj_b   = (const float*)d_in[3];
    const float* c1_um_wl = (const float*)d_in[4];
    const float* c1_um_bl = (const float*)d_in[5];
    const float* c1_um_wr = (const float*)d_in[6];
    const float* c1_mu_wl = (const float*)d_in[7];
    const float* c1_mu_bl = (const float*)d_in[8];
    const float* c1_mu_wr = (const float*)d_in[9];
    const float* c2_um_wl = (const float*)d_in[10];
    const float* c2_um_bl = (const float*)d_in[11];
    const float* c2_um_wr = (const float*)d_in[12];
    const float* c2_mu_wl = (const float*)d_in[13];
    const float* c2_mu_bl = (const float*)d_in[14];
    const float* c2_mu_wr = (const float*)d_in[15];
    const float* dec_w1   = (const float*)d_in[16];
    const float* dec_b1   = (const float*)d_in[17];
    const float* dec_w2   = (const float*)d_in[18];
    const float* dec_b2   = (const float*)d_in[19];
    const int* edge_src = (const int*)d_in[20];
    const int* edge_dst = (const int*)d_in[21];
    const int* lbl_src  = (const int*)d_in[22];
    const int* lbl_dst  = (const int*)d_in[23];

    const int M  = in_sizes[0] / 256;
    const int U  = in_sizes[1] / 64;
    const int E  = in_sizes[20];
    const int EL = in_sizes[22];
    float* out = (float*)d_out;

    char* ws = (char*)d_ws;
    size_t off = 0;
    auto alloc = [&](size_t bytes) -> void* {
        off = (off + 255) & ~(size_t)255;
        void* p = ws + off;
        off += bytes;
        return p;
    };
    int* deg_u  = (int*)alloc((size_t)U * 4);
    int* deg_m  = (int*)alloc((size_t)M * 4);
    int* scan_u = (int*)alloc((size_t)U * 4);
    int* scan_m = (int*)alloc((size_t)M * 4);
    int* bs_u   = (int*)alloc(1024);
    int* bs_m   = (int*)alloc(1024);
    int* off_u  = (int*)alloc((size_t)(U + 1) * 4);
    int* off_m  = (int*)alloc((size_t)(M + 1) * 4);
    int* pos_u  = (int*)alloc((size_t)(U + 1) * 4);
    int* pos_m  = (int*)alloc((size_t)(M + 1) * 4);
    int* adj_u  = (int*)alloc((size_t)E * 4);
    int* adj_m  = (int*)alloc((size_t)E * 4);
    float* movie0 = (float*)alloc((size_t)M * 64 * 4);   // later reused as B
    float* mean_m = (float*)alloc((size_t)M * 64 * 4);
    float* mean_u = (float*)alloc((size_t)U * 64 * 4);   // later reused as A (in-place)
    float* m_res  = (float*)alloc((size_t)M * 64 * 4);
    float* u_res  = (float*)alloc((size_t)U * 64 * 4);

    auto cdiv = [](int a, int b) { return (a + b - 1) / b; };

    hipMemsetAsync(deg_u, 0, (size_t)U * 4, stream);
    hipMemsetAsync(deg_m, 0, (size_t)M * 4, stream);
    k_count<<<cdiv(E, 256), 256, 0, stream>>>(edge_src, edge_dst, deg_u, deg_m, E);

    int nbm = cdiv(M, 1024), nbu = cdiv(U, 1024);
    k_scan_local<<<nbm, 256, 0, stream>>>(deg_m, scan_m, bs_m, M);
    k_scan_carry<<<1, 256, 0, stream>>>(bs_m, nbm);
    k_scan_off<<<cdiv(M + 1, 256), 256, 0, stream>>>(scan_m, bs_m, off_m, M);
    k_scan_local<<<nbu, 256, 0, stream>>>(deg_u, scan_u, bs_u, U);
    k_scan_carry<<<1, 256, 0, stream>>>(bs_u, nbu);
    k_scan_off<<<cdiv(U + 1, 256), 256, 0, stream>>>(scan_u, bs_u, off_u, U);

    hipMemcpyAsync(pos_m, off_m, (size_t)(M + 1) * 4, hipMemcpyDeviceToDevice, stream);
    hipMemcpyAsync(pos_u, off_u, (size_t)(U + 1) * 4, hipMemcpyDeviceToDevice, stream);
    k_fill<<<cdiv(E, 256), 256, 0, stream>>>(edge_src, edge_dst, pos_u, pos_m, adj_u, adj_m, E);

    k_proj<<<1024, 256, 0, stream>>>(movie_x, proj_w, proj_b, movie0, M);

    // layer 1
    k_agg<<<cdiv(M, 4), 256, 0, stream>>>(user_emb, adj_m, off_m, mean_m, M);
    k_agg<<<cdiv(U, 4), 256, 0, stream>>>(movie0, adj_u, off_u, mean_u, U);
    k_trans1<<<1024, 256, 0, stream>>>(mean_m, movie0, c1_um_wl, c1_um_bl, c1_um_wr, m_res, M);
    k_trans1<<<1024, 256, 0, stream>>>(mean_u, user_emb, c1_mu_wl, c1_mu_bl, c1_mu_wr, u_res, U);

    // layer 2
    k_agg<<<cdiv(M, 4), 256, 0, stream>>>(u_res, adj_m, off_m, mean_m, M);
    k_agg<<<cdiv(U, 4), 256, 0, stream>>>(m_res, adj_u, off_u, mean_u, U);
    // B = l2norm(m2) @ W1_bot   (into movie0 buffer)
    k_trans2<<<1024, 256, 0, stream>>>(mean_m, m_res, c2_um_wl, c2_um_bl, c2_um_wr,
                                       dec_w1 + 64 * 64, movie0, M);
    // A = l2norm(u2) @ W1_top   (in-place into mean_u)
    k_trans2<<<1024, 256, 0, stream>>>(mean_u, u_res, c2_mu_wl, c2_mu_bl, c2_mu_wr,
                                       dec_w1, mean_u, U);

    // decoder
    k_dec<<<cdiv(EL, 4), 256, 0, stream>>>(mean_u, movie0, lbl_src, lbl_dst,
                                           dec_b1, dec_w2, dec_b2, out, EL);
}

// Round 2
// 969.669 us; speedup vs baseline: 1.3015x; 1.3015x over previous
//
#include <hip/hip_runtime.h>

#define NXCD 8

// ---------------- degree count (XCD-partitioned by node range) ----------------
__global__ void k_count(const int* __restrict__ src, const int* __restrict__ dst,
                        int* __restrict__ deg_u, int* __restrict__ deg_m,
                        int E, int uq, int mq) {
    int x   = blockIdx.x & (NXCD - 1);
    int bx  = blockIdx.x >> 3;
    int nbx = gridDim.x >> 3;
    int ulo = x * uq, uhi = ulo + uq;
    int mlo = x * mq, mhi = mlo + mq;
    for (int e = bx * 256 + threadIdx.x; e < E; e += nbx * 256) {
        int s = src[e], d = dst[e];
        if (d >= mlo && d < mhi) atomicAdd(&deg_m[d], 1);
        if (s >= ulo && s < uhi) atomicAdd(&deg_u[s], 1);
    }
}

// ---------------- 2-level inclusive scan -> exclusive offsets ----------------
__global__ void k_scan_local(const int* __restrict__ deg, int* __restrict__ scanned,
                             int* __restrict__ bsums, int N) {
    __shared__ int s[1024];
    int base = blockIdx.x * 1024;
    for (int t = threadIdx.x; t < 1024; t += 256) {
        int i = base + t;
        s[t] = (i < N) ? deg[i] : 0;
    }
    __syncthreads();
    for (int d = 1; d < 1024; d <<= 1) {
        int vals[4];
        for (int j = 0; j < 4; ++j) {
            int t = threadIdx.x + j * 256;
            vals[j] = (t >= d) ? s[t - d] : 0;
        }
        __syncthreads();
        for (int j = 0; j < 4; ++j) {
            int t = threadIdx.x + j * 256;
            s[t] += vals[j];
        }
        __syncthreads();
    }
    for (int t = threadIdx.x; t < 1024; t += 256) {
        int i = base + t;
        if (i < N) scanned[i] = s[t];
    }
    if (threadIdx.x == 0) bsums[blockIdx.x] = s[1023];
}

__global__ void k_scan_carry(int* bsums, int nb) {
    __shared__ int s[256];
    int t = threadIdx.x;
    s[t] = (t < nb) ? bsums[t] : 0;
    __syncthreads();
    for (int d = 1; d < 256; d <<= 1) {
        int v = (t >= d) ? s[t - d] : 0;
        __syncthreads();
        s[t] += v;
        __syncthreads();
    }
    if (t < nb) bsums[t] = s[t];
}

__global__ void k_scan_off(const int* __restrict__ scanned, const int* __restrict__ bsums,
                           int* __restrict__ off, int N) {
    int i = blockIdx.x * 256 + threadIdx.x;
    if (i > N) return;
    int v = 0;
    if (i > 0) {
        int j = i - 1;
        int b = j >> 10;
        v = scanned[j] + (b > 0 ? bsums[b - 1] : 0);
    }
    off[i] = v;
}

// ---------------- CSR fill (XCD-partitioned: adj slices stay L2-resident) ----------------
__global__ void k_fill(const int* __restrict__ src, const int* __restrict__ dst,
                       int* __restrict__ pos_u, int* __restrict__ pos_m,
                       int* __restrict__ adj_u, int* __restrict__ adj_m,
                       int E, int uq, int mq) {
    int x   = blockIdx.x & (NXCD - 1);
    int bx  = blockIdx.x >> 3;
    int nbx = gridDim.x >> 3;
    int ulo = x * uq, uhi = ulo + uq;
    int mlo = x * mq, mhi = mlo + mq;
    for (int e = bx * 256 + threadIdx.x; e < E; e += nbx * 256) {
        int s = src[e], d = dst[e];
        if (d >= mlo && d < mhi) {
            int pm = atomicAdd(&pos_m[d], 1);
            adj_m[pm] = s;               // per-movie list of user sources
        }
        if (s >= ulo && s < uhi) {
            int pu = atomicAdd(&pos_u[s], 1);
            adj_u[pu] = d;               // per-user list of movie dsts
        }
    }
}

// ---------------- movie projection: relu(movie_x @ proj_w + b) ----------------
__global__ __launch_bounds__(256) void k_proj(const float* __restrict__ mx,
                                              const float* __restrict__ w,
                                              const float* __restrict__ b,
                                              float* __restrict__ out, int M) {
    __shared__ float ws[256 * 64];   // 64 KB
    __shared__ float xs[4][256];
    for (int t = threadIdx.x; t < 256 * 64 / 4; t += 256)
        ((float4*)ws)[t] = ((const float4*)w)[t];
    int nl = threadIdx.x >> 6, j = threadIdx.x & 63;
    for (int n0 = blockIdx.x * 4; n0 < M; n0 += gridDim.x * 4) {
        __syncthreads();
        for (int t = threadIdx.x; t < 256; t += 256) {
            int r = t >> 6, c4 = t & 63;
            int n = n0 + r;
            float4 v = (n < M) ? ((const float4*)mx)[n * 64 + c4] : make_float4(0.f, 0.f, 0.f, 0.f);
            ((float4*)&xs[r][0])[c4] = v;
        }
        __syncthreads();
        int n = n0 + nl;
        if (n < M) {
            float acc = b[j];
            #pragma unroll 8
            for (int k = 0; k < 256; ++k)
                acc += xs[nl][k] * ws[k * 64 + j];
            out[n * 64 + j] = fmaxf(acc, 0.f);
        }
    }
}

// ---------------- gather-side segment mean: one wave per node, 4 rows in flight ----------------
__global__ __launch_bounds__(256) void k_agg(const float* __restrict__ x,
                                             const int* __restrict__ adj,
                                             const int* __restrict__ off,
                                             float* __restrict__ out, int N) {
    int node = blockIdx.x * 4 + (threadIdx.x >> 6);
    if (node >= N) return;
    int lane = threadIdx.x & 63;
    int g = lane >> 4, i = lane & 15;
    int s0 = off[node], s1 = off[node + 1];
    float4 a = make_float4(0.f, 0.f, 0.f, 0.f);
    float4 b = make_float4(0.f, 0.f, 0.f, 0.f);
    int e = s0 + g;
    for (; e + 4 < s1; e += 8) {
        float4 v = ((const float4*)x)[(size_t)adj[e] * 16 + i];
        float4 w = ((const float4*)x)[(size_t)adj[e + 4] * 16 + i];
        a.x += v.x; a.y += v.y; a.z += v.z; a.w += v.w;
        b.x += w.x; b.y += w.y; b.z += w.z; b.w += w.w;
    }
    if (e < s1) {
        float4 v = ((const float4*)x)[(size_t)adj[e] * 16 + i];
        a.x += v.x; a.y += v.y; a.z += v.z; a.w += v.w;
    }
    a.x += b.x; a.y += b.y; a.z += b.z; a.w += b.w;
    #pragma unroll
    for (int o = 16; o <= 32; o <<= 1) {
        a.x += __shfl_xor(a.x, o, 64);
        a.y += __shfl_xor(a.y, o, 64);
        a.z += __shfl_xor(a.z, o, 64);
        a.w += __shfl_xor(a.w, o, 64);
    }
    int deg = s1 - s0;
    float scale = (deg > 0) ? 1.0f / (float)deg : 0.f;
    if (g == 0) {
        float4 r = make_float4(a.x * scale, a.y * scale, a.z * scale, a.w * scale);
        ((float4*)out)[(size_t)node * 16 + i] = r;
    }
}

// ---------------- layer-1 transform + relu + residual ----------------
// res = self + relu(mean @ wl + bl + self @ wr)
__global__ __launch_bounds__(256) void k_trans1(const float* __restrict__ mean,
                                                const float* __restrict__ self,
                                                const float* __restrict__ wl,
                                                const float* __restrict__ bl,
                                                const float* __restrict__ wr,
                                                float* __restrict__ res, int N) {
    __shared__ float wls[4096], wrs[4096];
    __shared__ float ms[4][64], ss[4][64];
    for (int t = threadIdx.x; t < 1024; t += 256) {
        ((float4*)wls)[t] = ((const float4*)wl)[t];
        ((float4*)wrs)[t] = ((const float4*)wr)[t];
    }
    int nl = threadIdx.x >> 6, lane = threadIdx.x & 63;
    float bias = bl[lane];
    for (int n0 = blockIdx.x * 4; n0 < N; n0 += gridDim.x * 4) {
        int n = n0 + nl;
        __syncthreads();
        if (n < N) {
            ms[nl][lane] = mean[n * 64 + lane];
            ss[nl][lane] = self[n * 64 + lane];
        }
        __syncthreads();
        if (n < N) {
            float acc = bias;
            #pragma unroll 16
            for (int k = 0; k < 64; ++k)
                acc += ms[nl][k] * wls[k * 64 + lane] + ss[nl][k] * wrs[k * 64 + lane];
            res[n * 64 + lane] = ss[nl][lane] + fmaxf(acc, 0.f);
        }
    }
}

// ---------------- layer-2 transform + l2norm + decoder half-projection ----------------
// t = mean @ wl + bl + res @ wr ; t /= max(||t||, 1e-12) ; outA = t @ wd
// NOTE: outA may alias mean (in-place, row-exclusive) -> no __restrict__ on those.
__global__ __launch_bounds__(256) void k_trans2(const float* mean,
                                                const float* __restrict__ res,
                                                const float* __restrict__ wl,
                                                const float* __restrict__ bl,
                                                const float* __restrict__ wr,
                                                const float* __restrict__ wd,
                                                float* outA, int N) {
    __shared__ float wls[4096], wrs[4096], wds[4096];
    __shared__ float ms[4][64], ss[4][64], ts[4][64];
    for (int t = threadIdx.x; t < 1024; t += 256) {
        ((float4*)wls)[t] = ((const float4*)wl)[t];
        ((float4*)wrs)[t] = ((const float4*)wr)[t];
        ((float4*)wds)[t] = ((const float4*)wd)[t];
    }
    int nl = threadIdx.x >> 6, lane = threadIdx.x & 63;
    float bias = bl[lane];
    for (int n0 = blockIdx.x * 4; n0 < N; n0 += gridDim.x * 4) {
        int n = n0 + nl;
        __syncthreads();
        if (n < N) {
            ms[nl][lane] = mean[n * 64 + lane];
            ss[nl][lane] = res[n * 64 + lane];
        }
        __syncthreads();
        if (n < N) {
            float acc = bias;
            #pragma unroll 16
            for (int k = 0; k < 64; ++k)
                acc += ms[nl][k] * wls[k * 64 + lane] + ss[nl][k] * wrs[k * 64 + lane];
            float sq = acc * acc;
            #pragma unroll
            for (int o = 32; o > 0; o >>= 1) sq += __shfl_xor(sq, o, 64);
            ts[nl][lane] = acc / fmaxf(sqrtf(sq), 1e-12f);
        }
        __syncthreads();
        if (n < N) {
            float a = 0.f;
            #pragma unroll 16
            for (int k = 0; k < 64; ++k)
                a += ts[nl][k] * wds[k * 64 + lane];
            outA[n * 64 + lane] = a;
        }
    }
}

// ---------------- decoder: out = relu(A[ls]+B[ld]+b1) . w2 + b2  (4 edges/wave) ----------------
__global__ __launch_bounds__(256) void k_dec(const float* __restrict__ A,
                                             const float* __restrict__ B,
                                             const int* __restrict__ ls,
                                             const int* __restrict__ ld,
                                             const float* __restrict__ b1,
                                             const float* __restrict__ w2,
                                             const float* __restrict__ b2,
                                             float* __restrict__ out, int EL) {
    int lane = threadIdx.x & 63;
    int g = lane >> 4, i = lane & 15;
    int e = blockIdx.x * 16 + (threadIdx.x >> 6) * 4 + g;
    if (e >= EL) return;
    int u = ls[e], m = ld[e];
    float4 av  = ((const float4*)A)[(size_t)u * 16 + i];
    float4 bv  = ((const float4*)B)[(size_t)m * 16 + i];
    float4 b1v = ((const float4*)b1)[i];
    float4 w2v = ((const float4*)w2)[i];
    float p = fmaxf(av.x + bv.x + b1v.x, 0.f) * w2v.x
            + fmaxf(av.y + bv.y + b1v.y, 0.f) * w2v.y
            + fmaxf(av.z + bv.z + b1v.z, 0.f) * w2v.z
            + fmaxf(av.w + bv.w + b1v.w, 0.f) * w2v.w;
    #pragma unroll
    for (int o = 1; o <= 8; o <<= 1) p += __shfl_xor(p, o, 64);
    if (i == 0) out[e] = p + b2[0];
}

extern "C" void kernel_launch(void* const* d_in, const int* in_sizes, int n_in,
                              void* d_out, int out_size, void* d_ws, size_t ws_size,
                              hipStream_t stream) {
    const float* movie_x  = (const float*)d_in[0];
    const float* user_emb = (const float*)d_in[1];
    const float* proj_w   = (const float*)d_in[2];
    const float* proj_b   = (const float*)d_in[3];
    const float* c1_um_wl = (const float*)d_in[4];
    const float* c1_um_bl = (const float*)d_in[5];
    const float* c1_um_wr = (const float*)d_in[6];
    const float* c1_mu_wl = (const float*)d_in[7];
    const float* c1_mu_bl = (const float*)d_in[8];
    const float* c1_mu_wr = (const float*)d_in[9];
    const float* c2_um_wl = (const float*)d_in[10];
    const float* c2_um_bl = (const float*)d_in[11];
    const float* c2_um_wr = (const float*)d_in[12];
    const float* c2_mu_wl = (const float*)d_in[13];
    const float* c2_mu_bl = (const float*)d_in[14];
    const float* c2_mu_wr = (const float*)d_in[15];
    const float* dec_w1   = (const float*)d_in[16];
    const float* dec_b1   = (const float*)d_in[17];
    const float* dec_w2   = (const float*)d_in[18];
    const float* dec_b2   = (const float*)d_in[19];
    const int* edge_src = (const int*)d_in[20];
    const int* edge_dst = (const int*)d_in[21];
    const int* lbl_src  = (const int*)d_in[22];
    const int* lbl_dst  = (const int*)d_in[23];

    const int M  = in_sizes[0] / 256;
    const int U  = in_sizes[1] / 64;
    const int E  = in_sizes[20];
    const int EL = in_sizes[22];
    float* out = (float*)d_out;

    char* ws = (char*)d_ws;
    size_t off = 0;
    auto alloc = [&](size_t bytes) -> void* {
        off = (off + 255) & ~(size_t)255;
        void* p = ws + off;
        off += bytes;
        return p;
    };
    int* deg_u  = (int*)alloc((size_t)U * 4);
    int* deg_m  = (int*)alloc((size_t)M * 4);
    int* scan_u = (int*)alloc((size_t)U * 4);
    int* scan_m = (int*)alloc((size_t)M * 4);
    int* bs_u   = (int*)alloc(1024);
    int* bs_m   = (int*)alloc(1024);
    int* off_u  = (int*)alloc((size_t)(U + 1) * 4);
    int* off_m  = (int*)alloc((size_t)(M + 1) * 4);
    int* pos_u  = (int*)alloc((size_t)(U + 1) * 4);
    int* pos_m  = (int*)alloc((size_t)(M + 1) * 4);
    int* adj_u  = (int*)alloc((size_t)E * 4);
    int* adj_m  = (int*)alloc((size_t)E * 4);
    float* movie0 = (float*)alloc((size_t)M * 64 * 4);   // later reused as B
    float* mean_m = (float*)alloc((size_t)M * 64 * 4);
    float* mean_u = (float*)alloc((size_t)U * 64 * 4);   // later reused as A (in-place)
    float* m_res  = (float*)alloc((size_t)M * 64 * 4);
    float* u_res  = (float*)alloc((size_t)U * 64 * 4);

    auto cdiv = [](int a, int b) { return (a + b - 1) / b; };
    const int uq = cdiv(U, NXCD), mq = cdiv(M, NXCD);

    hipMemsetAsync(deg_u, 0, (size_t)U * 4, stream);
    hipMemsetAsync(deg_m, 0, (size_t)M * 4, stream);
    k_count<<<1024, 256, 0, stream>>>(edge_src, edge_dst, deg_u, deg_m, E, uq, mq);

    int nbm = cdiv(M, 1024), nbu = cdiv(U, 1024);
    k_scan_local<<<nbm, 256, 0, stream>>>(deg_m, scan_m, bs_m, M);
    k_scan_carry<<<1, 256, 0, stream>>>(bs_m, nbm);
    k_scan_off<<<cdiv(M + 1, 256), 256, 0, stream>>>(scan_m, bs_m, off_m, M);
    k_scan_local<<<nbu, 256, 0, stream>>>(deg_u, scan_u, bs_u, U);
    k_scan_carry<<<1, 256, 0, stream>>>(bs_u, nbu);
    k_scan_off<<<cdiv(U + 1, 256), 256, 0, stream>>>(scan_u, bs_u, off_u, U);

    hipMemcpyAsync(pos_m, off_m, (size_t)(M + 1) * 4, hipMemcpyDeviceToDevice, stream);
    hipMemcpyAsync(pos_u, off_u, (size_t)(U + 1) * 4, hipMemcpyDeviceToDevice, stream);
    k_fill<<<1024, 256, 0, stream>>>(edge_src, edge_dst, pos_u, pos_m, adj_u, adj_m, E, uq, mq);

    k_proj<<<1024, 256, 0, stream>>>(movie_x, proj_w, proj_b, movie0, M);

    // layer 1
    k_agg<<<cdiv(M, 4), 256, 0, stream>>>(user_emb, adj_m, off_m, mean_m, M);
    k_agg<<<cdiv(U, 4), 256, 0, stream>>>(movie0, adj_u, off_u, mean_u, U);
    k_trans1<<<1024, 256, 0, stream>>>(mean_m, movie0, c1_um_wl, c1_um_bl, c1_um_wr, m_res, M);
    k_trans1<<<1024, 256, 0, stream>>>(mean_u, user_emb, c1_mu_wl, c1_mu_bl, c1_mu_wr, u_res, U);

    // layer 2
    k_agg<<<cdiv(M, 4), 256, 0, stream>>>(u_res, adj_m, off_m, mean_m, M);
    k_agg<<<cdiv(U, 4), 256, 0, stream>>>(m_res, adj_u, off_u, mean_u, U);
    // B = l2norm(m2) @ W1_bot   (into movie0 buffer)
    k_trans2<<<1024, 256, 0, stream>>>(mean_m, m_res, c2_um_wl, c2_um_bl, c2_um_wr,
                                       dec_w1 + 64 * 64, movie0, M);
    // A = l2norm(u2) @ W1_top   (in-place into mean_u)
    k_trans2<<<1024, 256, 0, stream>>>(mean_u, u_res, c2_mu_wl, c2_mu_bl, c2_mu_wr,
                                       dec_w1, mean_u, U);

    // decoder
    k_dec<<<cdiv(EL, 16), 256, 0, stream>>>(mean_u, movie0, lbl_src, lbl_dst,
                                            dec_b1, dec_w2, dec_b2, out, EL);
}

// Round 3
// 853.480 us; speedup vs baseline: 1.4786x; 1.1361x over previous
//
#include <hip/hip_runtime.h>

#define NXCD 8

// ---------------- fused degree count + per-edge rank (single pass) ----------------
// rank[e] = (slot within src's user list << 16) | (slot within dst's movie list)
__global__ void k_count_rank(const int* __restrict__ src, const int* __restrict__ dst,
                             int* __restrict__ deg_u, int* __restrict__ deg_m,
                             unsigned int* __restrict__ rank, int E) {
    int n4 = E >> 2;
    int i = blockIdx.x * 256 + threadIdx.x;
    if (i < n4) {
        int4 s4 = ((const int4*)src)[i];
        int4 d4 = ((const int4*)dst)[i];
        unsigned r0 = ((unsigned)atomicAdd(&deg_u[s4.x], 1) << 16) | (unsigned)atomicAdd(&deg_m[d4.x], 1);
        unsigned r1 = ((unsigned)atomicAdd(&deg_u[s4.y], 1) << 16) | (unsigned)atomicAdd(&deg_m[d4.y], 1);
        unsigned r2 = ((unsigned)atomicAdd(&deg_u[s4.z], 1) << 16) | (unsigned)atomicAdd(&deg_m[d4.z], 1);
        unsigned r3 = ((unsigned)atomicAdd(&deg_u[s4.w], 1) << 16) | (unsigned)atomicAdd(&deg_m[d4.w], 1);
        ((uint4*)rank)[i] = make_uint4(r0, r1, r2, r3);
    }
    if (i == 0) {
        for (int e = n4 * 4; e < E; ++e)
            rank[e] = ((unsigned)atomicAdd(&deg_u[src[e]], 1) << 16) | (unsigned)atomicAdd(&deg_m[dst[e]], 1);
    }
}

// ---------------- 2-level inclusive scan -> exclusive offsets ----------------
__global__ void k_scan_local(const int* __restrict__ deg, int* __restrict__ scanned,
                             int* __restrict__ bsums, int N) {
    __shared__ int s[1024];
    int base = blockIdx.x * 1024;
    for (int t = threadIdx.x; t < 1024; t += 256) {
        int i = base + t;
        s[t] = (i < N) ? deg[i] : 0;
    }
    __syncthreads();
    for (int d = 1; d < 1024; d <<= 1) {
        int vals[4];
        for (int j = 0; j < 4; ++j) {
            int t = threadIdx.x + j * 256;
            vals[j] = (t >= d) ? s[t - d] : 0;
        }
        __syncthreads();
        for (int j = 0; j < 4; ++j) {
            int t = threadIdx.x + j * 256;
            s[t] += vals[j];
        }
        __syncthreads();
    }
    for (int t = threadIdx.x; t < 1024; t += 256) {
        int i = base + t;
        if (i < N) scanned[i] = s[t];
    }
    if (threadIdx.x == 0) bsums[blockIdx.x] = s[1023];
}

__global__ void k_scan_carry(int* bsums, int nb) {
    __shared__ int s[256];
    int t = threadIdx.x;
    s[t] = (t < nb) ? bsums[t] : 0;
    __syncthreads();
    for (int d = 1; d < 256; d <<= 1) {
        int v = (t >= d) ? s[t - d] : 0;
        __syncthreads();
        s[t] += v;
        __syncthreads();
    }
    if (t < nb) bsums[t] = s[t];
}

__global__ void k_scan_off(const int* __restrict__ scanned, const int* __restrict__ bsums,
                           int* __restrict__ off, int N) {
    int i = blockIdx.x * 256 + threadIdx.x;
    if (i > N) return;
    int v = 0;
    if (i > 0) {
        int j = i - 1;
        int b = j >> 10;
        v = scanned[j] + (b > 0 ? bsums[b - 1] : 0);
    }
    off[i] = v;
}

// ---------------- atomic-free CSR fill (XCD-partitioned scattered stores) ----------------
__global__ void k_fill_rank(const int* __restrict__ src, const int* __restrict__ dst,
                            const unsigned int* __restrict__ rank,
                            const int* __restrict__ off_u, const int* __restrict__ off_m,
                            int* __restrict__ adj_u, int* __restrict__ adj_m,
                            int E, int uq, int mq) {
    int x   = blockIdx.x & (NXCD - 1);
    int bx  = blockIdx.x >> 3;
    int nbx = gridDim.x >> 3;
    int ulo = x * uq, uhi = ulo + uq;
    int mlo = x * mq, mhi = mlo + mq;
    for (int e = bx * 256 + threadIdx.x; e < E; e += nbx * 256) {
        int s = src[e], d = dst[e];
        unsigned r = rank[e];
        if (s >= ulo && s < uhi) adj_u[off_u[s] + (int)(r >> 16)] = d;     // user's movie list
        if (d >= mlo && d < mhi) adj_m[off_m[d] + (int)(r & 0xffffu)] = s; // movie's user list
    }
}

// ---------------- movie projection: relu(movie_x @ proj_w + b) ----------------
__global__ __launch_bounds__(256) void k_proj(const float* __restrict__ mx,
                                              const float* __restrict__ w,
                                              const float* __restrict__ b,
                                              float* __restrict__ out, int M) {
    __shared__ float ws[256 * 64];   // 64 KB
    __shared__ float xs[4][256];
    for (int t = threadIdx.x; t < 256 * 64 / 4; t += 256)
        ((float4*)ws)[t] = ((const float4*)w)[t];
    int nl = threadIdx.x >> 6, j = threadIdx.x & 63;
    for (int n0 = blockIdx.x * 4; n0 < M; n0 += gridDim.x * 4) {
        __syncthreads();
        for (int t = threadIdx.x; t < 256; t += 256) {
            int r = t >> 6, c4 = t & 63;
            int n = n0 + r;
            float4 v = (n < M) ? ((const float4*)mx)[n * 64 + c4] : make_float4(0.f, 0.f, 0.f, 0.f);
            ((float4*)&xs[r][0])[c4] = v;
        }
        __syncthreads();
        int n = n0 + nl;
        if (n < M) {
            float acc = b[j];
            #pragma unroll 8
            for (int k = 0; k < 256; ++k)
                acc += xs[nl][k] * ws[k * 64 + j];
            out[n * 64 + j] = fmaxf(acc, 0.f);
        }
    }
}

// ---------------- gather-side segment mean: one wave per node, 4 rows in flight ----------------
__global__ __launch_bounds__(256) void k_agg(const float* __restrict__ x,
                                             const int* __restrict__ adj,
                                             const int* __restrict__ off,
                                             float* __restrict__ out, int N) {
    int node = blockIdx.x * 4 + (threadIdx.x >> 6);
    if (node >= N) return;
    int lane = threadIdx.x & 63;
    int g = lane >> 4, i = lane & 15;
    int s0 = off[node], s1 = off[node + 1];
    float4 a = make_float4(0.f, 0.f, 0.f, 0.f);
    float4 b = make_float4(0.f, 0.f, 0.f, 0.f);
    int e = s0 + g;
    for (; e + 4 < s1; e += 8) {
        float4 v = ((const float4*)x)[(size_t)adj[e] * 16 + i];
        float4 w = ((const float4*)x)[(size_t)adj[e + 4] * 16 + i];
        a.x += v.x; a.y += v.y; a.z += v.z; a.w += v.w;
        b.x += w.x; b.y += w.y; b.z += w.z; b.w += w.w;
    }
    if (e < s1) {
        float4 v = ((const float4*)x)[(size_t)adj[e] * 16 + i];
        a.x += v.x; a.y += v.y; a.z += v.z; a.w += v.w;
    }
    a.x += b.x; a.y += b.y; a.z += b.z; a.w += b.w;
    #pragma unroll
    for (int o = 16; o <= 32; o <<= 1) {
        a.x += __shfl_xor(a.x, o, 64);
        a.y += __shfl_xor(a.y, o, 64);
        a.z += __shfl_xor(a.z, o, 64);
        a.w += __shfl_xor(a.w, o, 64);
    }
    int deg = s1 - s0;
    float scale = (deg > 0) ? 1.0f / (float)deg : 0.f;
    if (g == 0) {
        float4 r = make_float4(a.x * scale, a.y * scale, a.z * scale, a.w * scale);
        ((float4*)out)[(size_t)node * 16 + i] = r;
    }
}

// ---------------- layer-1 transform + relu + residual ----------------
// res = self + relu(mean @ wl + bl + self @ wr)
__global__ __launch_bounds__(256) void k_trans1(const float* __restrict__ mean,
                                                const float* __restrict__ self,
                                                const float* __restrict__ wl,
                                                const float* __restrict__ bl,
                                                const float* __restrict__ wr,
                                                float* __restrict__ res, int N) {
    __shared__ float wls[4096], wrs[4096];
    __shared__ float ms[4][64], ss[4][64];
    for (int t = threadIdx.x; t < 1024; t += 256) {
        ((float4*)wls)[t] = ((const float4*)wl)[t];
        ((float4*)wrs)[t] = ((const float4*)wr)[t];
    }
    int nl = threadIdx.x >> 6, lane = threadIdx.x & 63;
    float bias = bl[lane];
    for (int n0 = blockIdx.x * 4; n0 < N; n0 += gridDim.x * 4) {
        int n = n0 + nl;
        __syncthreads();
        if (n < N) {
            ms[nl][lane] = mean[n * 64 + lane];
            ss[nl][lane] = self[n * 64 + lane];
        }
        __syncthreads();
        if (n < N) {
            float acc = bias;
            #pragma unroll 16
            for (int k = 0; k < 64; ++k)
                acc += ms[nl][k] * wls[k * 64 + lane] + ss[nl][k] * wrs[k * 64 + lane];
            res[n * 64 + lane] = ss[nl][lane] + fmaxf(acc, 0.f);
        }
    }
}

// ---------------- layer-2 transform + l2norm + decoder half-projection ----------------
// t = mean @ wl + bl + res @ wr ; t /= max(||t||, 1e-12) ; outA = t @ wd
// NOTE: outA may alias mean (in-place, row-exclusive) -> no __restrict__ on those.
__global__ __launch_bounds__(256) void k_trans2(const float* mean,
                                                const float* __restrict__ res,
                                                const float* __restrict__ wl,
                                                const float* __restrict__ bl,
                                                const float* __restrict__ wr,
                                                const float* __restrict__ wd,
                                                float* outA, int N) {
    __shared__ float wls[4096], wrs[4096], wds[4096];
    __shared__ float ms[4][64], ss[4][64], ts[4][64];
    for (int t = threadIdx.x; t < 1024; t += 256) {
        ((float4*)wls)[t] = ((const float4*)wl)[t];
        ((float4*)wrs)[t] = ((const float4*)wr)[t];
        ((float4*)wds)[t] = ((const float4*)wd)[t];
    }
    int nl = threadIdx.x >> 6, lane = threadIdx.x & 63;
    float bias = bl[lane];
    for (int n0 = blockIdx.x * 4; n0 < N; n0 += gridDim.x * 4) {
        int n = n0 + nl;
        __syncthreads();
        if (n < N) {
            ms[nl][lane] = mean[n * 64 + lane];
            ss[nl][lane] = res[n * 64 + lane];
        }
        __syncthreads();
        if (n < N) {
            float acc = bias;
            #pragma unroll 16
            for (int k = 0; k < 64; ++k)
                acc += ms[nl][k] * wls[k * 64 + lane] + ss[nl][k] * wrs[k * 64 + lane];
            float sq = acc * acc;
            #pragma unroll
            for (int o = 32; o > 0; o >>= 1) sq += __shfl_xor(sq, o, 64);
            ts[nl][lane] = acc / fmaxf(sqrtf(sq), 1e-12f);
        }
        __syncthreads();
        if (n < N) {
            float a = 0.f;
            #pragma unroll 16
            for (int k = 0; k < 64; ++k)
                a += ts[nl][k] * wds[k * 64 + lane];
            outA[n * 64 + lane] = a;
        }
    }
}

// ---------------- decoder: out = relu(A[ls]+B[ld]+b1) . w2 + b2  (4 edges/wave) ----------------
__global__ __launch_bounds__(256) void k_dec(const float* __restrict__ A,
                                             const float* __restrict__ B,
                                             const int* __restrict__ ls,
                                             const int* __restrict__ ld,
                                             const float* __restrict__ b1,
                                             const float* __restrict__ w2,
                                             const float* __restrict__ b2,
                                             float* __restrict__ out, int EL) {
    int lane = threadIdx.x & 63;
    int g = lane >> 4, i = lane & 15;
    int e = blockIdx.x * 16 + (threadIdx.x >> 6) * 4 + g;
    if (e >= EL) return;
    int u = ls[e], m = ld[e];
    float4 av  = ((const float4*)A)[(size_t)u * 16 + i];
    float4 bv  = ((const float4*)B)[(size_t)m * 16 + i];
    float4 b1v = ((const float4*)b1)[i];
    float4 w2v = ((const float4*)w2)[i];
    float p = fmaxf(av.x + bv.x + b1v.x, 0.f) * w2v.x
            + fmaxf(av.y + bv.y + b1v.y, 0.f) * w2v.y
            + fmaxf(av.z + bv.z + b1v.z, 0.f) * w2v.z
            + fmaxf(av.w + bv.w + b1v.w, 0.f) * w2v.w;
    #pragma unroll
    for (int o = 1; o <= 8; o <<= 1) p += __shfl_xor(p, o, 64);
    if (i == 0) out[e] = p + b2[0];
}

extern "C" void kernel_launch(void* const* d_in, const int* in_sizes, int n_in,
                              void* d_out, int out_size, void* d_ws, size_t ws_size,
                              hipStream_t stream) {
    const float* movie_x  = (const float*)d_in[0];
    const float* user_emb = (const float*)d_in[1];
    const float* proj_w   = (const float*)d_in[2];
    const float* proj_b   = (const float*)d_in[3];
    const float* c1_um_wl = (const float*)d_in[4];
    const float* c1_um_bl = (const float*)d_in[5];
    const float* c1_um_wr = (const float*)d_in[6];
    const float* c1_mu_wl = (const float*)d_in[7];
    const float* c1_mu_bl = (const float*)d_in[8];
    const float* c1_mu_wr = (const float*)d_in[9];
    const float* c2_um_wl = (const float*)d_in[10];
    const float* c2_um_bl = (const float*)d_in[11];
    const float* c2_um_wr = (const float*)d_in[12];
    const float* c2_mu_wl = (const float*)d_in[13];
    const float* c2_mu_bl = (const float*)d_in[14];
    const float* c2_mu_wr = (const float*)d_in[15];
    const float* dec_w1   = (const float*)d_in[16];
    const float* dec_b1   = (const float*)d_in[17];
    const float* dec_w2   = (const float*)d_in[18];
    const float* dec_b2   = (const float*)d_in[19];
    const int* edge_src = (const int*)d_in[20];
    const int* edge_dst = (const int*)d_in[21];
    const int* lbl_src  = (const int*)d_in[22];
    const int* lbl_dst  = (const int*)d_in[23];

    const int M  = in_sizes[0] / 256;
    const int U  = in_sizes[1] / 64;
    const int E  = in_sizes[20];
    const int EL = in_sizes[22];
    float* out = (float*)d_out;

    char* ws = (char*)d_ws;
    size_t off = 0;
    auto alloc = [&](size_t bytes) -> void* {
        off = (off + 255) & ~(size_t)255;
        void* p = ws + off;
        off += bytes;
        return p;
    };
    int* deg_u  = (int*)alloc((size_t)U * 4);
    int* deg_m  = (int*)alloc((size_t)M * 4);
    int* scan_u = (int*)alloc((size_t)U * 4);
    int* scan_m = (int*)alloc((size_t)M * 4);
    int* bs_u   = (int*)alloc(1024);
    int* bs_m   = (int*)alloc(1024);
    int* off_u  = (int*)alloc((size_t)(U + 1) * 4);
    int* off_m  = (int*)alloc((size_t)(M + 1) * 4);
    int* adj_u  = (int*)alloc((size_t)E * 4);
    int* adj_m  = (int*)alloc((size_t)E * 4);
    float* movie0 = (float*)alloc((size_t)M * 64 * 4);   // later reused as B
    float* mean_m = (float*)alloc((size_t)M * 64 * 4);
    float* mean_u = (float*)alloc((size_t)U * 64 * 4);   // later reused as A (in-place)
    float* m_res  = (float*)alloc((size_t)M * 64 * 4);
    float* u_res  = (float*)alloc((size_t)U * 64 * 4);

    // rank aliases mean_u: written by k_count_rank/read by k_fill_rank, both
    // complete before mean_u's first write in the layer-1 aggregation.
    unsigned int* rank = (unsigned int*)mean_u;

    auto cdiv = [](int a, int b) { return (a + b - 1) / b; };
    const int uq = cdiv(U, NXCD), mq = cdiv(M, NXCD);

    hipMemsetAsync(deg_u, 0, (size_t)U * 4, stream);
    hipMemsetAsync(deg_m, 0, (size_t)M * 4, stream);
    k_count_rank<<<cdiv(E >> 2, 256), 256, 0, stream>>>(edge_src, edge_dst, deg_u, deg_m, rank, E);

    int nbm = cdiv(M, 1024), nbu = cdiv(U, 1024);
    k_scan_local<<<nbm, 256, 0, stream>>>(deg_m, scan_m, bs_m, M);
    k_scan_carry<<<1, 256, 0, stream>>>(bs_m, nbm);
    k_scan_off<<<cdiv(M + 1, 256), 256, 0, stream>>>(scan_m, bs_m, off_m, M);
    k_scan_local<<<nbu, 256, 0, stream>>>(deg_u, scan_u, bs_u, U);
    k_scan_carry<<<1, 256, 0, stream>>>(bs_u, nbu);
    k_scan_off<<<cdiv(U + 1, 256), 256, 0, stream>>>(scan_u, bs_u, off_u, U);

    k_fill_rank<<<1024, 256, 0, stream>>>(edge_src, edge_dst, rank, off_u, off_m,
                                          adj_u, adj_m, E, uq, mq);

    k_proj<<<1024, 256, 0, stream>>>(movie_x, proj_w, proj_b, movie0, M);

    // layer 1
    k_agg<<<cdiv(M, 4), 256, 0, stream>>>(user_emb, adj_m, off_m, mean_m, M);
    k_agg<<<cdiv(U, 4), 256, 0, stream>>>(movie0, adj_u, off_u, mean_u, U);
    k_trans1<<<1024, 256, 0, stream>>>(mean_m, movie0, c1_um_wl, c1_um_bl, c1_um_wr, m_res, M);
    k_trans1<<<1024, 256, 0, stream>>>(mean_u, user_emb, c1_mu_wl, c1_mu_bl, c1_mu_wr, u_res, U);

    // layer 2
    k_agg<<<cdiv(M, 4), 256, 0, stream>>>(u_res, adj_m, off_m, mean_m, M);
    k_agg<<<cdiv(U, 4), 256, 0, stream>>>(m_res, adj_u, off_u, mean_u, U);
    // B = l2norm(m2) @ W1_bot   (into movie0 buffer)
    k_trans2<<<1024, 256, 0, stream>>>(mean_m, m_res, c2_um_wl, c2_um_bl, c2_um_wr,
                                       dec_w1 + 64 * 64, movie0, M);
    // A = l2norm(u2) @ W1_top   (in-place into mean_u)
    k_trans2<<<1024, 256, 0, stream>>>(mean_u, u_res, c2_mu_wl, c2_mu_bl, c2_mu_wr,
                                       dec_w1, mean_u, U);

    // decoder
    k_dec<<<cdiv(EL, 16), 256, 0, stream>>>(mean_u, movie0, lbl_src, lbl_dst,
                                            dec_b1, dec_w2, dec_b2, out, EL);
}

// Round 4
// 733.063 us; speedup vs baseline: 1.7215x; 1.1643x over previous
//
#include <hip/hip_runtime.h>

#define NB 256   // blocks for hist/scatter passes
#define ND 256   // digit buckets

// ---------------- pass A: per-block digit histograms for BOTH sides ----------------
__global__ __launch_bounds__(256) void k_hist2(const int* __restrict__ src, const int* __restrict__ dst,
                                               int* __restrict__ hist_u, int* __restrict__ hist_m,
                                               int E, int chunk) {
    __shared__ int hu[ND], hm[ND];
    for (int t = threadIdx.x; t < ND; t += 256) { hu[t] = 0; hm[t] = 0; }
    __syncthreads();
    int b = blockIdx.x;
    int e0 = b * chunk, e1 = min(E, e0 + chunk);
    for (int e = e0 + threadIdx.x; e < e1; e += 256) {
        atomicAdd(&hu[src[e] >> 9], 1);
        atomicAdd(&hm[dst[e] >> 7], 1);
    }
    __syncthreads();
    for (int t = threadIdx.x; t < ND; t += 256) {
        hist_u[t * NB + b] = hu[t];   // digit-major layout -> flat scan gives scatter bases
        hist_m[t * NB + b] = hm[t];
    }
}

// ---------------- 2-level inclusive scan -> exclusive offsets ----------------
__global__ void k_scan_local(const int* __restrict__ deg, int* __restrict__ scanned,
                             int* __restrict__ bsums, int N) {
    __shared__ int s[1024];
    int base = blockIdx.x * 1024;
    for (int t = threadIdx.x; t < 1024; t += 256) {
        int i = base + t;
        s[t] = (i < N) ? deg[i] : 0;
    }
    __syncthreads();
    for (int d = 1; d < 1024; d <<= 1) {
        int vals[4];
        for (int j = 0; j < 4; ++j) {
            int t = threadIdx.x + j * 256;
            vals[j] = (t >= d) ? s[t - d] : 0;
        }
        __syncthreads();
        for (int j = 0; j < 4; ++j) {
            int t = threadIdx.x + j * 256;
            s[t] += vals[j];
        }
        __syncthreads();
    }
    for (int t = threadIdx.x; t < 1024; t += 256) {
        int i = base + t;
        if (i < N) scanned[i] = s[t];
    }
    if (threadIdx.x == 0) bsums[blockIdx.x] = s[1023];
}

__global__ void k_scan_carry(int* bsums, int nb) {
    __shared__ int s[256];
    int t = threadIdx.x;
    s[t] = (t < nb) ? bsums[t] : 0;
    __syncthreads();
    for (int d = 1; d < 256; d <<= 1) {
        int v = (t >= d) ? s[t - d] : 0;
        __syncthreads();
        s[t] += v;
        __syncthreads();
    }
    if (t < nb) bsums[t] = s[t];
}

__global__ void k_scan_off(const int* __restrict__ scanned, const int* __restrict__ bsums,
                           int* __restrict__ off, int N) {
    int i = blockIdx.x * 256 + threadIdx.x;
    if (i > N) return;
    int v = 0;
    if (i > 0) {
        int j = i - 1;
        int b = j >> 10;
        v = scanned[j] + (b > 0 ? bsums[b - 1] : 0);
    }
    off[i] = v;
}

// ---------------- pass A scatter: partition edges by top digit (no global atomics) ----------------
__global__ __launch_bounds__(256) void k_scatter(const int* __restrict__ key, const int* __restrict__ val,
                                                 const int* __restrict__ off_flat, int2* __restrict__ tmp,
                                                 int E, int chunk, int shift) {
    __shared__ int cnt[ND];
    for (int t = threadIdx.x; t < ND; t += 256) cnt[t] = 0;
    __syncthreads();
    int b = blockIdx.x;
    int e0 = b * chunk, e1 = min(E, e0 + chunk);
    for (int e = e0 + threadIdx.x; e < e1; e += 256) {
        int k = key[e];
        int d = k >> shift;
        int r = atomicAdd(&cnt[d], 1);           // LDS-only rank
        tmp[off_flat[d * NB + b] + r] = make_int2(k, val[e]);
    }
}

// ---------------- pass B: per-bucket counting sort -> adj + node offsets ----------------
template <int WIDTH>
__global__ __launch_bounds__(256) void k_bucket(const int2* __restrict__ tmp,
                                                const int* __restrict__ off_flat,
                                                int* __restrict__ adj, int* __restrict__ off_node,
                                                int E, int shift, int NN) {
    __shared__ int cnt[WIDTH];
    int d = blockIdx.x;
    int bstart = off_flat[d * NB];
    int bend   = off_flat[(d + 1) * NB];         // off_flat has ND*NB+1 entries; last == E
    for (int t = threadIdx.x; t < WIDTH; t += 256) cnt[t] = 0;
    __syncthreads();
    int bsz = bend - bstart;
    for (int i = threadIdx.x; i < bsz; i += 256)
        atomicAdd(&cnt[tmp[bstart + i].x & (WIDTH - 1)], 1);
    __syncthreads();
    // exclusive scan of cnt[0..WIDTH) by wave 0
    int lane = threadIdx.x;
    if (lane < 64) {
        constexpr int EPL = WIDTH >> 6;
        int vals[EPL];
        int tot = 0;
        #pragma unroll
        for (int j = 0; j < EPL; ++j) { vals[j] = cnt[lane * EPL + j]; tot += vals[j]; }
        int inc = tot;
        #pragma unroll
        for (int o = 1; o < 64; o <<= 1) {
            int tsh = __shfl_up(inc, o, 64);
            if (lane >= o) inc += tsh;
        }
        int ex = inc - tot;
        #pragma unroll
        for (int j = 0; j < EPL; ++j) { cnt[lane * EPL + j] = ex; ex += vals[j]; }
    }
    __syncthreads();
    // emit node offsets (deg = off[n+1]-off[n] downstream)
    int base_node = d << shift;
    for (int t = threadIdx.x; t < WIDTH; t += 256) {
        int node = base_node + t;
        if (node < NN) off_node[node] = bstart + cnt[t];
    }
    if (d == 0 && threadIdx.x == 0) off_node[NN] = E;
    __syncthreads();
    // scatter within bucket
    for (int i = threadIdx.x; i < bsz; i += 256) {
        int2 e = tmp[bstart + i];
        int r = atomicAdd(&cnt[e.x & (WIDTH - 1)], 1);
        adj[bstart + r] = e.y;
    }
}

// ---------------- movie projection: relu(movie_x @ proj_w + b) ----------------
__global__ __launch_bounds__(256) void k_proj(const float* __restrict__ mx,
                                              const float* __restrict__ w,
                                              const float* __restrict__ b,
                                              float* __restrict__ out, int M) {
    __shared__ float ws[256 * 64];   // 64 KB
    __shared__ float xs[4][256];
    for (int t = threadIdx.x; t < 256 * 64 / 4; t += 256)
        ((float4*)ws)[t] = ((const float4*)w)[t];
    int nl = threadIdx.x >> 6, j = threadIdx.x & 63;
    for (int n0 = blockIdx.x * 4; n0 < M; n0 += gridDim.x * 4) {
        __syncthreads();
        for (int t = threadIdx.x; t < 256; t += 256) {
            int r = t >> 6, c4 = t & 63;
            int n = n0 + r;
            float4 v = (n < M) ? ((const float4*)mx)[n * 64 + c4] : make_float4(0.f, 0.f, 0.f, 0.f);
            ((float4*)&xs[r][0])[c4] = v;
        }
        __syncthreads();
        int n = n0 + nl;
        if (n < M) {
            float acc = b[j];
            #pragma unroll 8
            for (int k = 0; k < 256; ++k)
                acc += xs[nl][k] * ws[k * 64 + j];
            out[n * 64 + j] = fmaxf(acc, 0.f);
        }
    }
}

// ---------------- gather-side segment mean: one wave per node, 4 rows in flight ----------------
__global__ __launch_bounds__(256) void k_agg(const float* __restrict__ x,
                                             const int* __restrict__ adj,
                                             const int* __restrict__ off,
                                             float* __restrict__ out, int N) {
    int node = blockIdx.x * 4 + (threadIdx.x >> 6);
    if (node >= N) return;
    int lane = threadIdx.x & 63;
    int g = lane >> 4, i = lane & 15;
    int s0 = off[node], s1 = off[node + 1];
    float4 a = make_float4(0.f, 0.f, 0.f, 0.f);
    float4 b = make_float4(0.f, 0.f, 0.f, 0.f);
    int e = s0 + g;
    for (; e + 4 < s1; e += 8) {
        float4 v = ((const float4*)x)[(size_t)adj[e] * 16 + i];
        float4 w = ((const float4*)x)[(size_t)adj[e + 4] * 16 + i];
        a.x += v.x; a.y += v.y; a.z += v.z; a.w += v.w;
        b.x += w.x; b.y += w.y; b.z += w.z; b.w += w.w;
    }
    if (e < s1) {
        float4 v = ((const float4*)x)[(size_t)adj[e] * 16 + i];
        a.x += v.x; a.y += v.y; a.z += v.z; a.w += v.w;
    }
    a.x += b.x; a.y += b.y; a.z += b.z; a.w += b.w;
    #pragma unroll
    for (int o = 16; o <= 32; o <<= 1) {
        a.x += __shfl_xor(a.x, o, 64);
        a.y += __shfl_xor(a.y, o, 64);
        a.z += __shfl_xor(a.z, o, 64);
        a.w += __shfl_xor(a.w, o, 64);
    }
    int deg = s1 - s0;
    float scale = (deg > 0) ? 1.0f / (float)deg : 0.f;
    if (g == 0) {
        float4 r = make_float4(a.x * scale, a.y * scale, a.z * scale, a.w * scale);
        ((float4*)out)[(size_t)node * 16 + i] = r;
    }
}

// ---------------- layer-1 transform + relu + residual ----------------
__global__ __launch_bounds__(256) void k_trans1(const float* __restrict__ mean,
                                                const float* __restrict__ self,
                                                const float* __restrict__ wl,
                                                const float* __restrict__ bl,
                                                const float* __restrict__ wr,
                                                float* __restrict__ res, int N) {
    __shared__ float wls[4096], wrs[4096];
    __shared__ float ms[4][64], ss[4][64];
    for (int t = threadIdx.x; t < 1024; t += 256) {
        ((float4*)wls)[t] = ((const float4*)wl)[t];
        ((float4*)wrs)[t] = ((const float4*)wr)[t];
    }
    int nl = threadIdx.x >> 6, lane = threadIdx.x & 63;
    float bias = bl[lane];
    for (int n0 = blockIdx.x * 4; n0 < N; n0 += gridDim.x * 4) {
        int n = n0 + nl;
        __syncthreads();
        if (n < N) {
            ms[nl][lane] = mean[n * 64 + lane];
            ss[nl][lane] = self[n * 64 + lane];
        }
        __syncthreads();
        if (n < N) {
            float acc = bias;
            #pragma unroll 16
            for (int k = 0; k < 64; ++k)
                acc += ms[nl][k] * wls[k * 64 + lane] + ss[nl][k] * wrs[k * 64 + lane];
            res[n * 64 + lane] = ss[nl][lane] + fmaxf(acc, 0.f);
        }
    }
}

// ---------------- layer-2 transform + l2norm + decoder half-projection ----------------
__global__ __launch_bounds__(256) void k_trans2(const float* mean,
                                                const float* __restrict__ res,
                                                const float* __restrict__ wl,
                                                const float* __restrict__ bl,
                                                const float* __restrict__ wr,
                                                const float* __restrict__ wd,
                                                float* outA, int N) {
    __shared__ float wls[4096], wrs[4096], wds[4096];
    __shared__ float ms[4][64], ss[4][64], ts[4][64];
    for (int t = threadIdx.x; t < 1024; t += 256) {
        ((float4*)wls)[t] = ((const float4*)wl)[t];
        ((float4*)wrs)[t] = ((const float4*)wr)[t];
        ((float4*)wds)[t] = ((const float4*)wd)[t];
    }
    int nl = threadIdx.x >> 6, lane = threadIdx.x & 63;
    float bias = bl[lane];
    for (int n0 = blockIdx.x * 4; n0 < N; n0 += gridDim.x * 4) {
        int n = n0 + nl;
        __syncthreads();
        if (n < N) {
            ms[nl][lane] = mean[n * 64 + lane];
            ss[nl][lane] = res[n * 64 + lane];
        }
        __syncthreads();
        if (n < N) {
            float acc = bias;
            #pragma unroll 16
            for (int k = 0; k < 64; ++k)
                acc += ms[nl][k] * wls[k * 64 + lane] + ss[nl][k] * wrs[k * 64 + lane];
            float sq = acc * acc;
            #pragma unroll
            for (int o = 32; o > 0; o >>= 1) sq += __shfl_xor(sq, o, 64);
            ts[nl][lane] = acc / fmaxf(sqrtf(sq), 1e-12f);
        }
        __syncthreads();
        if (n < N) {
            float a = 0.f;
            #pragma unroll 16
            for (int k = 0; k < 64; ++k)
                a += ts[nl][k] * wds[k * 64 + lane];
            outA[n * 64 + lane] = a;
        }
    }
}

// ---------------- decoder: out = relu(A[ls]+B[ld]+b1) . w2 + b2  (4 edges/wave) ----------------
__global__ __launch_bounds__(256) void k_dec(const float* __restrict__ A,
                                             const float* __restrict__ B,
                                             const int* __restrict__ ls,
                                             const int* __restrict__ ld,
                                             const float* __restrict__ b1,
                                             const float* __restrict__ w2,
                                             const float* __restrict__ b2,
                                             float* __restrict__ out, int EL) {
    int lane = threadIdx.x & 63;
    int g = lane >> 4, i = lane & 15;
    int e = blockIdx.x * 16 + (threadIdx.x >> 6) * 4 + g;
    if (e >= EL) return;
    int u = ls[e], m = ld[e];
    float4 av  = ((const float4*)A)[(size_t)u * 16 + i];
    float4 bv  = ((const float4*)B)[(size_t)m * 16 + i];
    float4 b1v = ((const float4*)b1)[i];
    float4 w2v = ((const float4*)w2)[i];
    float p = fmaxf(av.x + bv.x + b1v.x, 0.f) * w2v.x
            + fmaxf(av.y + bv.y + b1v.y, 0.f) * w2v.y
            + fmaxf(av.z + bv.z + b1v.z, 0.f) * w2v.z
            + fmaxf(av.w + bv.w + b1v.w, 0.f) * w2v.w;
    #pragma unroll
    for (int o = 1; o <= 8; o <<= 1) p += __shfl_xor(p, o, 64);
    if (i == 0) out[e] = p + b2[0];
}

extern "C" void kernel_launch(void* const* d_in, const int* in_sizes, int n_in,
                              void* d_out, int out_size, void* d_ws, size_t ws_size,
                              hipStream_t stream) {
    const float* movie_x  = (const float*)d_in[0];
    const float* user_emb = (const float*)d_in[1];
    const float* proj_w   = (const float*)d_in[2];
    const float* proj_b   = (const float*)d_in[3];
    const float* c1_um_wl = (const float*)d_in[4];
    const float* c1_um_bl = (const float*)d_in[5];
    const float* c1_um_wr = (const float*)d_in[6];
    const float* c1_mu_wl = (const float*)d_in[7];
    const float* c1_mu_bl = (const float*)d_in[8];
    const float* c1_mu_wr = (const float*)d_in[9];
    const float* c2_um_wl = (const float*)d_in[10];
    const float* c2_um_bl = (const float*)d_in[11];
    const float* c2_um_wr = (const float*)d_in[12];
    const float* c2_mu_wl = (const float*)d_in[13];
    const float* c2_mu_bl = (const float*)d_in[14];
    const float* c2_mu_wr = (const float*)d_in[15];
    const float* dec_w1   = (const float*)d_in[16];
    const float* dec_b1   = (const float*)d_in[17];
    const float* dec_w2   = (const float*)d_in[18];
    const float* dec_b2   = (const float*)d_in[19];
    const int* edge_src = (const int*)d_in[20];
    const int* edge_dst = (const int*)d_in[21];
    const int* lbl_src  = (const int*)d_in[22];
    const int* lbl_dst  = (const int*)d_in[23];

    const int M  = in_sizes[0] / 256;
    const int U  = in_sizes[1] / 64;
    const int E  = in_sizes[20];
    const int EL = in_sizes[22];
    float* out = (float*)d_out;

    char* ws = (char*)d_ws;
    size_t off = 0;
    auto alloc = [&](size_t bytes) -> void* {
        off = (off + 255) & ~(size_t)255;
        void* p = ws + off;
        off += bytes;
        return p;
    };
    int* bsums  = (int*)alloc(1024);
    int* off_u  = (int*)alloc((size_t)(U + 1) * 4);
    int* off_m  = (int*)alloc((size_t)(M + 1) * 4);
    int* adj_u  = (int*)alloc((size_t)E * 4);
    int* adj_m  = (int*)alloc((size_t)E * 4);
    float* movie0 = (float*)alloc((size_t)M * 64 * 4);   // later reused as B
    float* mean_m = (float*)alloc((size_t)M * 64 * 4);
    float* mean_u = (float*)alloc((size_t)U * 64 * 4);   // later reused as A (in-place)
    float* m_res  = (float*)alloc((size_t)M * 64 * 4);
    float* u_res  = (float*)alloc((size_t)U * 64 * 4);

    // CSR-build scratch aliases (all dead before mean_m/mean_u first written):
    int*  hist_u   = (int*)mean_m;            // ND*NB ints = 256 KB
    int*  hist_m   = hist_u + ND * NB;        // 256 KB
    int*  scanned  = hist_m + ND * NB;        // 256 KB
    int*  off_flat = scanned + ND * NB;       // ND*NB+1 ints
    int2* tmp      = (int2*)mean_u;           // E*8 = 16 MB (< 25.6 MB)

    auto cdiv = [](int a, int b) { return (a + b - 1) / b; };
    const int chunk = cdiv(E, NB);
    const int NF = ND * NB;                   // 65536 flat counters

    hipMemsetAsync(hist_u, 0, (size_t)NF * 4, stream);
    hipMemsetAsync(hist_m, 0, (size_t)NF * 4, stream);
    k_hist2<<<NB, 256, 0, stream>>>(edge_src, edge_dst, hist_u, hist_m, E, chunk);

    // movie-side CSR (bucket by dst>>7, width 128)
    k_scan_local<<<NF / 1024, 256, 0, stream>>>(hist_m, scanned, bsums, NF);
    k_scan_carry<<<1, 256, 0, stream>>>(bsums, NF / 1024);
    k_scan_off<<<cdiv(NF + 1, 256), 256, 0, stream>>>(scanned, bsums, off_flat, NF);
    k_scatter<<<NB, 256, 0, stream>>>(edge_dst, edge_src, off_flat, tmp, E, chunk, 7);
    k_bucket<128><<<ND, 256, 0, stream>>>(tmp, off_flat, adj_m, off_m, E, 7, M);

    // user-side CSR (bucket by src>>9, width 512)
    k_scan_local<<<NF / 1024, 256, 0, stream>>>(hist_u, scanned, bsums, NF);
    k_scan_carry<<<1, 256, 0, stream>>>(bsums, NF / 1024);
    k_scan_off<<<cdiv(NF + 1, 256), 256, 0, stream>>>(scanned, bsums, off_flat, NF);
    k_scatter<<<NB, 256, 0, stream>>>(edge_src, edge_dst, off_flat, tmp, E, chunk, 9);
    k_bucket<512><<<ND, 256, 0, stream>>>(tmp, off_flat, adj_u, off_u, E, 9, U);

    k_proj<<<1024, 256, 0, stream>>>(movie_x, proj_w, proj_b, movie0, M);

    // layer 1
    k_agg<<<cdiv(M, 4), 256, 0, stream>>>(user_emb, adj_m, off_m, mean_m, M);
    k_agg<<<cdiv(U, 4), 256, 0, stream>>>(movie0, adj_u, off_u, mean_u, U);
    k_trans1<<<1024, 256, 0, stream>>>(mean_m, movie0, c1_um_wl, c1_um_bl, c1_um_wr, m_res, M);
    k_trans1<<<1024, 256, 0, stream>>>(mean_u, user_emb, c1_mu_wl, c1_mu_bl, c1_mu_wr, u_res, U);

    // layer 2
    k_agg<<<cdiv(M, 4), 256, 0, stream>>>(u_res, adj_m, off_m, mean_m, M);
    k_agg<<<cdiv(U, 4), 256, 0, stream>>>(m_res, adj_u, off_u, mean_u, U);
    // B = l2norm(m2) @ W1_bot   (into movie0 buffer)
    k_trans2<<<1024, 256, 0, stream>>>(mean_m, m_res, c2_um_wl, c2_um_bl, c2_um_wr,
                                       dec_w1 + 64 * 64, movie0, M);
    // A = l2norm(u2) @ W1_top   (in-place into mean_u)
    k_trans2<<<1024, 256, 0, stream>>>(mean_u, u_res, c2_mu_wl, c2_mu_bl, c2_mu_wr,
                                       dec_w1, mean_u, U);

    // decoder
    k_dec<<<cdiv(EL, 16), 256, 0, stream>>>(mean_u, movie0, lbl_src, lbl_dst,
                                            dec_b1, dec_w2, dec_b2, out, EL);
}